// Round 2
// baseline (911.586 us; speedup 1.0000x reference)
//
#include <hip/hip_runtime.h>
#include <math.h>

#define NMS_THRESH 0.7f
#define NANCH 36864
#define TOPK 6000
#define NWORDS 94    // ceil(6000/64)
#define POSTK 300
#define MAXCAND 10240

// ---------------- conv 3x3 + bias + relu, batch 0 only ----------------
// grid 512 = co_tile(32) * y_tile(16); block 256 (4 waves)
// block: 16 co x (4 rows x 64 cols). wave w owns co slice [co0+4w, +4).
// thread: 4px (consecutive x) x 4co. Weights via scalar (s_load) broadcast.
__global__ __launch_bounds__(256, 2)
void k_conv(const float* __restrict__ feat, const float* __restrict__ W,
            const float* __restrict__ bias, float* __restrict__ tout)
{
    __shared__ float sF[16][6][68];   // ci x (4+2 rows) x (66 used, pad to 68 for 16B rows)

    const int blk = blockIdx.x;
    const int cob = (blk >> 4) << 4;      // 0..496 step 16
    const int y0  = (blk & 15) << 2;      // 0..60 step 4
    const int tid = threadIdx.x;
    const int lane = tid & 63;
    const int wid = __builtin_amdgcn_readfirstlane(tid >> 6);  // wave id 0..3 (uniform)
    const int co0 = cob + (wid << 2);
    const int ly = lane >> 4;             // row 0..3
    const int lx = (lane & 15) << 2;      // x base 0..60 step 4

    float acc[4][4];                      // [px i][co j]
    #pragma unroll
    for (int i = 0; i < 4; ++i)
        #pragma unroll
        for (int j = 0; j < 4; ++j) acc[i][j] = 0.f;

    for (int cc = 0; cc < 32; ++cc) {
        const int ci0 = cc << 4;
        __syncthreads();
        // stage 16 ci x 6 rows x 66 cols (halo) = 6528 slots incl pad
        #pragma unroll
        for (int q = 0; q < 26; ++q) {
            int idx = q * 256 + tid;
            if (idx < 6528) {
                int ci  = idx / 408; int r = idx - ci * 408;
                int row = r / 68;    int col = r - row * 68;
                int gy = y0 - 1 + row, gx = col - 1;
                float v = 0.f;
                if (col < 66 && (unsigned)gy < 64u && (unsigned)gx < 64u)
                    v = feat[((size_t)(ci0 + ci) << 12) + (gy << 6) + gx];
                sF[ci][row][col] = v;
            }
        }
        __syncthreads();
        #pragma unroll 2
        for (int ci = 0; ci < 16; ++ci) {
            const float* wr = W + (size_t)co0 * 4608 + (size_t)(ci0 + ci) * 9;
            #pragma unroll
            for (int ky = 0; ky < 3; ++ky) {
                float fr[6];
                float4 f4 = *(const float4*)&sF[ci][ly + ky][lx];
                float2 f2 = *(const float2*)&sF[ci][ly + ky][lx + 4];
                fr[0] = f4.x; fr[1] = f4.y; fr[2] = f4.z; fr[3] = f4.w;
                fr[4] = f2.x; fr[5] = f2.y;
                float wt[4][3];                      // uniform -> SGPR s_loads
                #pragma unroll
                for (int j = 0; j < 4; ++j)
                    #pragma unroll
                    for (int kx = 0; kx < 3; ++kx)
                        wt[j][kx] = wr[(size_t)j * 4608 + ky * 3 + kx];
                #pragma unroll
                for (int kx = 0; kx < 3; ++kx)       // same (ci,ky,kx,i,j) order as round 0
                    #pragma unroll
                    for (int i = 0; i < 4; ++i)
                        #pragma unroll
                        for (int j = 0; j < 4; ++j)
                            acc[i][j] = fmaf(fr[i + kx], wt[j][kx], acc[i][j]);
            }
        }
    }
    const int y = y0 + ly;
    #pragma unroll
    for (int j = 0; j < 4; ++j) {
        const float bv = bias[co0 + j];
        float4 o;
        o.x = fmaxf(acc[0][j] + bv, 0.f);
        o.y = fmaxf(acc[1][j] + bv, 0.f);
        o.z = fmaxf(acc[2][j] + bv, 0.f);
        o.w = fmaxf(acc[3][j] + bv, 0.f);
        *(float4*)&tout[((size_t)(co0 + j) << 12) + (y << 6) + lx] = o;
    }
}

// ---------------- head-weight repack: wall[ci][48] ----------------
__global__ void k_wall(const float* __restrict__ cls_w, const float* __restrict__ reg_w,
                       float* __restrict__ wall)
{
    int idx = blockIdx.x * 256 + threadIdx.x;
    if (idx >= 512 * 48) return;
    int ci = idx / 48, ch = idx - ci * 48;
    float v = 0.f;
    if (ch < 9) v = cls_w[ch * 512 + ci];
    else if (ch < 45) v = reg_w[(ch - 9) * 512 + ci];
    wall[idx] = v;
}

// ---------------- 1x1 heads: all 45 channels, t read once ----------------
// grid 64 x block 64; thread = 1 px, sequential ci (bitwise == round 0)
__global__ __launch_bounds__(64, 4)
void k_heads(const float* __restrict__ t, const float* __restrict__ wall,
             const float* __restrict__ cls_b, const float* __restrict__ reg_b,
             float* __restrict__ heads)
{
    const int px = blockIdx.x * 64 + threadIdx.x;
    float acc[45];
    #pragma unroll
    for (int ch = 0; ch < 9; ++ch) acc[ch] = cls_b[ch];
    #pragma unroll
    for (int ch = 0; ch < 36; ++ch) acc[9 + ch] = reg_b[ch];
    #pragma unroll 4
    for (int ci = 0; ci < 512; ++ci) {
        float v = t[((size_t)ci << 12) + px];
        const float* wrow = wall + ci * 48;      // uniform -> s_loads
        #pragma unroll
        for (int ch = 0; ch < 45; ++ch)
            acc[ch] = fmaf(v, wrow[ch], acc[ch]);
    }
    #pragma unroll
    for (int ch = 0; ch < 45; ++ch)
        heads[((size_t)ch << 12) + px] = acc[ch];
}

// ---------------- per-anchor decode, sigmoid, clip, validity ----------------
__global__ void k_decode(const float* __restrict__ heads,
                         float* __restrict__ score, float* __restrict__ validf,
                         float* __restrict__ box)
{
    int idx = blockIdx.x * 256 + threadIdx.x;
    if (idx >= NANCH) return;
    int p = idx / 9, a = idx - p * 9;
    int yq = p >> 6, xq = p & 63;
    const double scl[3] = {128.0, 256.0, 512.0};
    const double rat[3] = {0.5, 1.0, 2.0};
    double s = scl[a / 3], r = rat[a % 3];
    float bw = (float)(s * sqrt(1.0 / r) * 0.5);
    float bh = (float)(s * sqrt(r) * 0.5);
    float sx = xq * 16.0f + 8.0f;
    float sy = yq * 16.0f + 8.0f;
    float a0 = sx - bw, a1 = sy - bh, a2 = sx + bw, a3 = sy + bh;
    float wa = a2 - a0, ha = a3 - a1;
    float cx = a0 + 0.5f * wa, cy = a1 + 0.5f * ha;
    float logit = heads[(size_t)a * 4096 + p];
    float dx = heads[(size_t)(9  + 4 * a) * 4096 + p];
    float dy = heads[(size_t)(10 + 4 * a) * 4096 + p];
    float dw = fminf(heads[(size_t)(11 + 4 * a) * 4096 + p], 4.135166556742356f);
    float dh = fminf(heads[(size_t)(12 + 4 * a) * 4096 + p], 4.135166556742356f);
    float pcx = dx * wa + cx, pcy = dy * ha + cy;
    float pw = expf(dw) * wa, ph = expf(dh) * ha;
    float x1 = pcx - 0.5f * pw, y1 = pcy - 0.5f * ph;
    float x2 = pcx + 0.5f * pw, y2 = pcy + 0.5f * ph;
    x1 = fminf(fmaxf(x1, 0.f), 1024.f); y1 = fminf(fmaxf(y1, 0.f), 1024.f);
    x2 = fminf(fmaxf(x2, 0.f), 1024.f); y2 = fminf(fmaxf(y2, 0.f), 1024.f);
    float wv = x2 - x1, hv = y2 - y1;
    float sc = 1.f / (1.f + expf(-logit));
    score[idx]  = sc;
    validf[idx] = (wv >= 1.f && hv >= 1.f) ? 1.f : 0.f;
    box[idx * 4 + 0] = x1; box[idx * 4 + 1] = y1;
    box[idx * 4 + 2] = x2; box[idx * 4 + 3] = y2;
}

// ---------------- top-k cutoff machinery ----------------
__global__ void k_zero(unsigned* __restrict__ p) {
    int i = blockIdx.x * 256 + threadIdx.x;
    if (i < 8256) p[i] = 0u;   // hist(4096) + hist2(4096) + meta(64)
}

__global__ void k_hist1(const float* __restrict__ score, unsigned* __restrict__ hist) {
    __shared__ unsigned lh[4096];
    int tid = threadIdx.x;
    for (int q = tid; q < 4096; q += 256) lh[q] = 0u;
    __syncthreads();
    int idx = blockIdx.x * 256 + tid;
    unsigned b = __float_as_uint(score[idx]) >> 19;
    atomicAdd(&lh[b], 1u);
    __syncthreads();
    for (int q = tid; q < 4096; q += 256) if (lh[q]) atomicAdd(&hist[q], lh[q]);
}

__global__ void k_cut1(const unsigned* __restrict__ hist, unsigned* __restrict__ meta) {
    __shared__ unsigned hh[4096];
    __shared__ unsigned gs[256];
    int tid = threadIdx.x;
    for (int q = tid; q < 4096; q += 256) hh[q] = hist[q];
    __syncthreads();
    unsigned s = 0;
    #pragma unroll
    for (int k = 0; k < 16; ++k) s += hh[tid * 16 + k];
    gs[tid] = s;
    __syncthreads();
    if (tid == 0) {
        unsigned cum = 0;
        for (int g = 255; g >= 0; --g) {
            if (cum + gs[g] >= (unsigned)TOPK) {
                for (int b = g * 16 + 15; b >= g * 16; --b) {
                    if (cum + hh[b] >= (unsigned)TOPK) { meta[2] = (unsigned)b; meta[3] = cum; break; }
                    cum += hh[b];
                }
                break;
            }
            cum += gs[g];
        }
    }
}

__global__ void k_hist2(const float* __restrict__ score, const unsigned* __restrict__ meta,
                        unsigned* __restrict__ hist2) {
    int idx = blockIdx.x * 256 + threadIdx.x;
    unsigned bits = __float_as_uint(score[idx]);
    if ((bits >> 19) == meta[2]) atomicAdd(&hist2[(bits >> 7) & 0xFFFu], 1u);
}

__global__ void k_cut2(const unsigned* __restrict__ hist2, unsigned* __restrict__ meta) {
    __shared__ unsigned hh[4096];
    __shared__ unsigned gs[256];
    int tid = threadIdx.x;
    for (int q = tid; q < 4096; q += 256) hh[q] = hist2[q];
    __syncthreads();
    unsigned s = 0;
    #pragma unroll
    for (int k = 0; k < 16; ++k) s += hh[tid * 16 + k];
    gs[tid] = s;
    __syncthreads();
    if (tid == 0) {
        unsigned cum = meta[3];
        unsigned B = meta[2];
        unsigned cut = B << 19;
        for (int g = 255; g >= 0; --g) {
            if (cum + gs[g] >= (unsigned)TOPK) {
                for (int b = g * 16 + 15; b >= g * 16; --b) {
                    cum += hh[b];
                    if (cum >= (unsigned)TOPK) { cut = (B << 19) | ((unsigned)b << 7); break; }
                }
                break;
            }
            cum += gs[g];
        }
        meta[0] = cut;
    }
}

__global__ void k_compact(const float* __restrict__ score, unsigned* __restrict__ meta,
                          int* __restrict__ cand) {
    int idx = blockIdx.x * 256 + threadIdx.x;
    unsigned bits = __float_as_uint(score[idx]);
    if (bits >= meta[0]) {
        unsigned pos = atomicAdd(&meta[1], 1u);
        if (pos < (unsigned)MAXCAND) cand[pos] = idx;
    }
}

// ---------------- exact ranks for candidates only ----------------
// grid 320; block 256 = 32 cand-lanes x 8 j-splits
__global__ __launch_bounds__(256, 4)
void k_rank(const float* __restrict__ score, const float* __restrict__ validf,
            const float* __restrict__ box, const unsigned* __restrict__ meta,
            const int* __restrict__ cand,
            float* __restrict__ score6, float* __restrict__ sc6,
            float* __restrict__ box6)
{
    __shared__ int pc[8][32];
    const int tid = threadIdx.x;
    const int il = tid & 31, js = tid >> 5;
    unsigned ncand = meta[1]; if (ncand > (unsigned)MAXCAND) ncand = MAXCAND;
    const int c = blockIdx.x * 32 + il;
    int i = -1; float si = 0.f;
    if (c < (int)ncand) { i = cand[c]; si = score[i]; }
    int cnt = 0;
    if (i >= 0) {
        const float4* sp = (const float4*)score;
        const int j0 = js * 4608;
        for (int q = 0; q < 1152; ++q) {
            float4 v = sp[j0 / 4 + q];
            int jb = j0 + q * 4;
            cnt += (v.x > si) || (v.x == si && (jb + 0) < i);
            cnt += (v.y > si) || (v.y == si && (jb + 1) < i);
            cnt += (v.z > si) || (v.z == si && (jb + 2) < i);
            cnt += (v.w > si) || (v.w == si && (jb + 3) < i);
        }
    }
    pc[js][il] = cnt;
    __syncthreads();
    if (js == 0 && i >= 0) {
        int rank = 0;
        #pragma unroll
        for (int q = 0; q < 8; ++q) rank += pc[q][il];
        if (rank < TOPK) {
            score6[rank] = si;
            sc6[rank] = (validf[i] != 0.f) ? si : -INFINITY;
            box6[rank * 4 + 0] = box[i * 4 + 0];
            box6[rank * 4 + 1] = box[i * 4 + 1];
            box6[rank * 4 + 2] = box[i * 4 + 2];
            box6[rank * 4 + 3] = box[i * 4 + 3];
        }
    }
}

// ---------------- pairwise IoU bitmask ----------------
__global__ void k_iou(const float* __restrict__ box6,
                      unsigned long long* __restrict__ mask)
{
    __shared__ float jb[64][4];
    const int blk = blockIdx.x;
    const int rb = blk / NWORDS, wb = blk - rb * NWORDS;
    const int tid = threadIdx.x;
    int j = wb * 64 + tid;
    if (j < TOPK) {
        jb[tid][0] = box6[j * 4 + 0]; jb[tid][1] = box6[j * 4 + 1];
        jb[tid][2] = box6[j * 4 + 2]; jb[tid][3] = box6[j * 4 + 3];
    } else {
        jb[tid][0] = 0.f; jb[tid][1] = 0.f; jb[tid][2] = 0.f; jb[tid][3] = 0.f;
    }
    __syncthreads();
    int i = rb * 64 + tid;
    if (i >= TOPK) return;
    float x1 = box6[i * 4], y1 = box6[i * 4 + 1], x2 = box6[i * 4 + 2], y2 = box6[i * 4 + 3];
    float ai = (x2 - x1) * (y2 - y1);
    unsigned long long bits = 0;
    for (int q = 0; q < 64; ++q) {
        float bx1 = jb[q][0], by1 = jb[q][1], bx2 = jb[q][2], by2 = jb[q][3];
        float xl = fmaxf(x1, bx1), yt = fmaxf(y1, by1);
        float xr = fminf(x2, bx2), yb = fminf(y2, by2);
        float inter = fmaxf(xr - xl, 0.f) * fmaxf(yb - yt, 0.f);
        float aj = (bx2 - bx1) * (by2 - by1);
        float iou = inter / (ai + aj - inter);
        if (iou > NMS_THRESH) bits |= (1ull << q);
    }
    mask[(size_t)i * NWORDS + wb] = bits;
}

// ---------------- sequential greedy NMS scan + output ----------------
__global__ void k_scan(const float* __restrict__ sc6, const float* __restrict__ score6,
                       const float* __restrict__ box6,
                       const unsigned long long* __restrict__ mask,
                       float* __restrict__ out)
{
    __shared__ unsigned long long remv[NWORDS];
    __shared__ int kept[POSTK];
    __shared__ int kcnt;
    __shared__ int kbs_s;
    __shared__ int klist[64];
    const int tid = threadIdx.x;
    for (int w = tid; w < NWORDS; w += 256) remv[w] = 0ull;
    if (tid == 0) kcnt = 0;
    __syncthreads();
    for (int b = 0; b < NWORDS; ++b) {
        if (tid < 64) {
            int i = b * 64 + tid;
            bool v = (i < TOPK) && (sc6[i] > -INFINITY);
            unsigned long long mi = 0ull;
            if (v) mi = mask[(size_t)i * NWORDS + b];
            unsigned long long validb = __ballot(v);
            unsigned long long cur = remv[b];
            int kc = kcnt;
            int kb = 0;
            unsigned long long cand2 = validb & ~cur;
            while (cand2 != 0ull && kc < POSTK) {
                int rr = __builtin_ctzll(cand2);
                unsigned long long mr = __shfl(mi, rr, 64);
                if (tid == 0) { kept[kc] = b * 64 + rr; klist[kb] = rr; }
                ++kb; ++kc;
                cur |= mr | (1ull << rr);
                cand2 = validb & ~cur;
            }
            if (tid == 0) { kcnt = kc; kbs_s = kb; remv[b] = cur; }
        }
        __syncthreads();
        int kb = kbs_s;
        if (kb > 0) {
            int w = b + 1 + tid;
            if (w < NWORDS) {
                unsigned long long acc = remv[w];
                for (int q = 0; q < kb; ++q) {
                    int rr = klist[q];
                    acc |= mask[(size_t)(b * 64 + rr) * NWORDS + w];
                }
                remv[w] = acc;
            }
        }
        __syncthreads();
        if (kcnt >= POSTK) break;
    }
    __syncthreads();
    int kc = kcnt;
    for (int n = tid; n < POSTK; n += 256) {
        float o0 = 0.f, o1 = 0.f, o2 = 0.f, o3 = 0.f, o4 = 0.f;
        if (n < kc) {
            int i = kept[n];
            o0 = box6[i * 4 + 0]; o1 = box6[i * 4 + 1];
            o2 = box6[i * 4 + 2]; o3 = box6[i * 4 + 3];
            o4 = score6[i];
        }
        out[n * 5 + 0] = o0; out[n * 5 + 1] = o1; out[n * 5 + 2] = o2;
        out[n * 5 + 3] = o3; out[n * 5 + 4] = o4;
    }
}

extern "C" void kernel_launch(void* const* d_in, const int* in_sizes, int n_in,
                              void* d_out, int out_size, void* d_ws, size_t ws_size,
                              hipStream_t stream)
{
    (void)in_sizes; (void)n_in; (void)out_size; (void)ws_size;
    const float* feat   = (const float*)d_in[1];   // (8,512,64,64) -> batch 0 only
    const float* conv_w = (const float*)d_in[2];
    const float* conv_b = (const float*)d_in[3];
    const float* cls_w  = (const float*)d_in[4];
    const float* cls_b  = (const float*)d_in[5];
    const float* reg_w  = (const float*)d_in[6];
    const float* reg_b  = (const float*)d_in[7];

    char* ws = (char*)d_ws;
    float*    t      = (float*)(ws + 0);          // 8,388,608 B (dead after k_heads)
    float*    wall   = (float*)(ws + 8388608);    //    98,304 B
    float*    heads  = (float*)(ws + 8486912);    //   737,280 B (dead after k_decode)
    unsigned* hist   = (unsigned*)(ws + 8486912); // overlay on heads (used after decode)
    unsigned* hist2  = (unsigned*)(ws + 8503296);
    unsigned* meta   = (unsigned*)(ws + 8519680); // [0]=cut [1]=ncand [2]=bin [3]=above
    int*      cand   = (int*)(ws + 8520192);      //    40,960 B
    float*    score  = (float*)(ws + 9224192);    //   147,456 B
    float*    validf = (float*)(ws + 9371648);    //   147,456 B
    float*    box    = (float*)(ws + 9519104);    //   589,824 B
    float*    score6 = (float*)(ws + 10108928);   //    24,576 B
    float*    sc6    = (float*)(ws + 10133504);   //    24,576 B
    float*    box6   = (float*)(ws + 10158080);   //    98,304 B  (end 10,256,384)
    unsigned long long* mask = (unsigned long long*)(ws + 0);  // reuse t: 4,512,000 B

    k_wall   <<<96,   256, 0, stream>>>(cls_w, reg_w, wall);
    k_conv   <<<512,  256, 0, stream>>>(feat, conv_w, conv_b, t);
    k_heads  <<<64,   64,  0, stream>>>(t, wall, cls_b, reg_b, heads);
    k_decode <<<144,  256, 0, stream>>>(heads, score, validf, box);
    k_zero   <<<33,   256, 0, stream>>>(hist);            // hist+hist2+meta contiguous
    k_hist1  <<<144,  256, 0, stream>>>(score, hist);
    k_cut1   <<<1,    256, 0, stream>>>(hist, meta);
    k_hist2  <<<144,  256, 0, stream>>>(score, meta, hist2);
    k_cut2   <<<1,    256, 0, stream>>>(hist2, meta);
    k_compact<<<144,  256, 0, stream>>>(score, meta, cand);
    k_rank   <<<320,  256, 0, stream>>>(score, validf, box, meta, cand, score6, sc6, box6);
    k_iou    <<<NWORDS * NWORDS, 64, 0, stream>>>(box6, mask);
    k_scan   <<<1,    256, 0, stream>>>(sc6, score6, box6, mask, (float*)d_out);
}